// Round 6
// baseline (187.750 us; speedup 1.0000x reference)
//
#include <hip/hip_runtime.h>
#include <hip/hip_bf16.h>
#include <math.h>

typedef __attribute__((ext_vector_type(8))) short short8;
typedef __attribute__((ext_vector_type(4))) short short4v;
typedef __attribute__((ext_vector_type(4))) float float4v;
typedef unsigned short ushort_t;

constexpr int NPTS = 32768;  // B*N
constexpr int NN   = 16384;  // points per batch
constexpr int KK   = 32;     // neighbors
constexpr int CC   = 128;    // channels
constexpr int GRP  = 16;     // points per block -> grid 2048
constexpr int SG   = 40;     // geo LDS row stride (shorts): 80 B -> 2-way banks (free)
constexpr int SR   = 136;    // res LDS row stride (shorts): 272 B -> 2-way banks (free)
#define LN_EPS 1e-5f

// d_ws layout (bytes)
constexpr size_t WS_WP   = 0;        // W' swizzled: 20*128*8 bf16 = 40960 B
constexpr size_t WS_WO   = 40960;    // w_out swizzled: 128*128 bf16 = 32768 B
constexpr size_t WS_BE   = 73728;    // beff: 128 f32 = 512 B
constexpr size_t WS_FB   = 74240;    // features bf16: 32768*128*2 = 8388608 B
constexpr size_t WS_NEED = WS_FB + (size_t)NPTS * CC * 2;

__device__ __forceinline__ short f2bs(float x) {
    return (short)__builtin_bit_cast(unsigned short, __float2bfloat16(x));
}
__device__ __forceinline__ float bs2f(ushort_t u) {
    return __uint_as_float(((unsigned)u) << 16);
}

// ---------------- prep A: weights fold + swizzle (2 blocks, LDS-staged) ----------------
__global__ __launch_bounds__(256) void prep_weights(
    const float* __restrict__ w_pos, const float* __restrict__ b_pos,
    const float* __restrict__ w_gcm, const float* __restrict__ b_gcm,
    const float* __restrict__ w_out,
    short* __restrict__ wsWp, short* __restrict__ wsWo, float* __restrict__ wsBeff)
{
    __shared__ float sW[128 * 128];
    __shared__ float sPG[10 * 128];
    const int t = threadIdx.x;

    if (blockIdx.x == 1) {     // ---- w_out: coalesced stage -> swizzle [(k/8)(n)(k%8)] ----
        for (int e = t; e < 4096; e += 256) ((float4*)sW)[e] = ((const float4*)w_out)[e];
        __syncthreads();
        for (int e = t; e < 128 * 128; e += 256) {
            int j = e & 7, n = (e >> 3) & 127, g = e >> 10;
            wsWo[e] = f2bs(sW[(g * 8 + j) * 128 + n]);
        }
        return;
    }
    // ---- block 0: stage w_gcm, fold w_pos/b_pos, emit W' + beff ----
    for (int e = t; e < 4096; e += 256) ((float4*)sW)[e] = ((const float4*)w_gcm)[e];
    __syncthreads();
    {
        const int c  = t & 127;
        const int gb = t >> 7;
        for (int gi = 0; gi < 5; ++gi) {
            const int g = gi * 2 + gb;
            float s = 0.f;
            for (int r = 0; r < 128; ++r) s += w_pos[g * 128 + r] * sW[r * 128 + c];
            sPG[g * 128 + c] = s;
        }
        if (t < 128) {
            float wb = b_gcm[t];
            for (int r = 0; r < 128; ++r) wb += b_pos[r] * sW[r * 128 + t];
            wsBeff[t] = wb;
        }
    }
    __syncthreads();
    for (int e = t; e < 20 * 128 * 8; e += 256) {
        const int j = e & 7, n = (e >> 3) & 127, g = e >> 10;
        const int k = g * 8 + j;
        const float v = (k < 128) ? sW[k * 128 + n] : (k < 138 ? sPG[(k - 128) * 128 + n] : 0.f);
        wsWp[e] = f2bs(v);
    }
}

// ---------------- prep B: features f32 -> bf16 (coalesced, no LDS) ----------------
__global__ __launch_bounds__(256) void prep_convert(
    const float* __restrict__ features, ushort_t* __restrict__ featbf)
{
    const int t = threadIdx.x;
    #pragma unroll
    for (int i = 0; i < 8; ++i) {
        const int f4 = blockIdx.x * 2048 + i * 256 + t;    // float4 units
        const float4 a = ((const float4*)features)[f4];
        short4v v; v[0]=f2bs(a.x); v[1]=f2bs(a.y); v[2]=f2bs(a.z); v[3]=f2bs(a.w);
        ((short4v*)featbf)[f4] = v;
    }
}

// ---------------- main: pair-of-points per iteration; wave = (point-half, col-half) ----------------
// Per wave per pair: 40 MFMA(16x16x32) from 10 ds_read_b128 A-frags -> 4:1 reuse
template<int DMA>
__global__ __launch_bounds__(256) void bridge_main(
    const float* __restrict__ points, const float* __restrict__ features,
    const int*   __restrict__ gidx,
    const short* __restrict__ wsWp, const short* __restrict__ wsWo,
    const float* __restrict__ wsBeff, const ushort_t* __restrict__ featbf,
    const float* __restrict__ b_out, const float* __restrict__ ln_g,
    const float* __restrict__ ln_b,
    float* __restrict__ out)
{
    __shared__ short sA[2][2][KK * CC];   // [pair-buf][point-in-pair][row*CC], XOR-chunk-swizzled
    __shared__ short sG[2][2][KK * SG];   // geo chunks 16..19 (10 real + zeros)
    __shared__ short sRes[GRP * SR];
    __shared__ int   sIdx[GRP * KK];      // 512 neighbor indices
    __shared__ float sPS[4][GRP], sPQ[4][GRP];

    const int t = threadIdx.x, wv = t >> 6, lane = t & 63;
    const int quad = (t >> 4) & 3, m = t & 15;
    const int ph = wv >> 1;               // point-in-pair handled by this wave
    const int ch = wv & 1;                // column half (0: cols 0-63, 1: 64-127)
    const int g0 = blockIdx.x * GRP;
    const int nbase = (g0 >= NN) ? NN : 0;

    // ---- stage idx + zero geo pad chunks ----
    sIdx[t]       = gidx[(size_t)g0 * KK + t];
    sIdx[t + 256] = gidx[(size_t)g0 * KK + t + 256];
    {   // zero shorts 16..31 of every geo row (2 buf x 2 te x 32 rows x 2 halves = 256)
        const int bu = t >> 7, te = (t >> 6) & 1, row = (t >> 1) & 31, h = t & 1;
        *(short8*)&sG[bu][te][row * SG + 16 + h * 8] = (short8)0;
    }

    // ---- B fragments (4 n-tiles x 5 k-steps, register-resident: 80 VGPR) ----
    short8 bWp[5][4];
    #pragma unroll
    for (int ks = 0; ks < 5; ++ks)
        #pragma unroll
        for (int n = 0; n < 4; ++n)
            bWp[ks][n] = *((const short8*)wsWp + ((ks * 4 + quad) * 128 + ch * 64 + n * 16 + m));
    float beffv[4];
    #pragma unroll
    for (int n = 0; n < 4; ++n) beffv[n] = wsBeff[ch * 64 + n * 16 + m];

    __syncthreads();   // sIdx + sG pads ready

    // ---- pipeline lambdas ----
    float gcx, gcy, gcz, ggx, ggy, ggz;             // geo regs (lane<16)
    float resn[4], resc[4];                          // residual feature (own point)
    float4 fb0[4], fb1[4];                           // fallback gather regs

    auto geo_load = [&](int pair) {
        if (lane < 16) {
            const int e = wv * 16 + lane;            // 0..63 geo rows
            const int te = e >> 5, row = e & 31;
            const int pt = g0 + pair * 2 + te;
            const int kn = nbase + sIdx[(pair * 2 + te) * KK + row];
            gcx = points[(size_t)pt * 3 + 0]; gcy = points[(size_t)pt * 3 + 1]; gcz = points[(size_t)pt * 3 + 2];
            ggx = points[(size_t)kn * 3 + 0]; ggy = points[(size_t)kn * 3 + 1]; ggz = points[(size_t)kn * 3 + 2];
        }
    };
    auto geo_store = [&](int pair, int buf) {
        if (lane < 16) {
            const int e = wv * 16 + lane;
            const int te = e >> 5, row = e & 31;
            const float dx = ggx - gcx, dy = ggy - gcy, dz = ggz - gcz;
            const float dist = sqrtf(dx * dx + dy * dy + dz * dz);
            short8 v0, v1 = (short8)0;
            v0[0]=f2bs(gcx); v0[1]=f2bs(gcy); v0[2]=f2bs(gcz);
            v0[3]=f2bs(ggx); v0[4]=f2bs(ggy); v0[5]=f2bs(ggz);
            v0[6]=f2bs(dx);  v0[7]=f2bs(dy);
            v1[0]=f2bs(dz);  v1[1]=f2bs(dist);
            *(short8*)&sG[buf][te][row * SG + 0] = v0;
            *(short8*)&sG[buf][te][row * SG + 8] = v1;
        }
    };
    auto res_load = [&](int pair) {
        const int pt = g0 + pair * 2 + ph;
        #pragma unroll
        for (int n = 0; n < 4; ++n) {
            if constexpr (DMA) resn[n] = bs2f(featbf[(size_t)pt * CC + ch * 64 + n * 16 + m]);
            else               resn[n] = features[(size_t)pt * CC + ch * 64 + n * 16 + m];
        }
    };
    auto gather_issue = [&](int pair, int buf) {
        #pragma unroll
        for (int i = 0; i < 4; ++i) {
            const int e = wv * 4 + i;                // 0..15 issue slots
            const int te = e >> 3, rg = e & 7;       // tile, row-group (4 rows)
            const int row = rg * 4 + (lane >> 4);
            const int kn  = nbase + sIdx[(pair * 2 + te) * KK + row];
            const int gc  = (lane & 15) ^ (row & 15);   // XOR chunk swizzle
            if constexpr (DMA) {
                const ushort_t* gp = featbf + (size_t)kn * CC + gc * 8;
                short* lp = &sA[buf][te][rg * 4 * CC];   // wave-uniform; lane -> +lane*16B
                __builtin_amdgcn_global_load_lds((const __attribute__((address_space(1))) void*)gp,
                                                 (__attribute__((address_space(3))) void*)lp, 16, 0, 0);
            } else {
                const float4* fp = (const float4*)(features + (size_t)kn * CC + gc * 8);
                fb0[i] = fp[0]; fb1[i] = fp[1];
            }
        }
    };
    auto gather_store = [&](int buf) {               // fallback only
        #pragma unroll
        for (int i = 0; i < 4; ++i) {
            const int e = wv * 4 + i;
            const int te = e >> 3, rg = e & 7;
            const int row = rg * 4 + (lane >> 4);
            short8 v;
            v[0]=f2bs(fb0[i].x); v[1]=f2bs(fb0[i].y); v[2]=f2bs(fb0[i].z); v[3]=f2bs(fb0[i].w);
            v[4]=f2bs(fb1[i].x); v[5]=f2bs(fb1[i].y); v[6]=f2bs(fb1[i].z); v[7]=f2bs(fb1[i].w);
            *(short8*)&sA[buf][te][row * CC + (lane & 15) * 8] = v;
        }
    };

    // ---- prologue: pair 0 ----
    geo_load(0);
    res_load(0);
    gather_issue(0, 0);
    geo_store(0, 0);
    if constexpr (!DMA) gather_store(0);
    #pragma unroll
    for (int n = 0; n < 4; ++n) resc[n] = resn[n];
    __syncthreads();   // drains DMA (compiler vmcnt(0) before barrier) -> pair 0 resident

    // loop-invariant A offsets (shorts)
    int offA[4];
    #pragma unroll
    for (int ks = 0; ks < 4; ++ks) offA[ks] = m * CC + (((ks * 4 + quad) ^ m) * 8);
    const int offG = m * SG + quad * 8;

    for (int pair = 0; pair < GRP / 2; ++pair) {
        const int buf = pair & 1, nb = buf ^ 1;
        if (pair < GRP / 2 - 1) {
            geo_load(pair + 1);
            res_load(pair + 1);
            gather_issue(pair + 1, nb);              // in flight across this pair's MFMA
        }

        const short* at = sA[buf][ph];
        const short* gt = sG[buf][ph];
        float4v acc[2][4] = {};
        #pragma unroll
        for (int ks = 0; ks < 4; ++ks) {
            const short8 a0 = *(const short8*)(at + offA[ks]);
            const short8 a1 = *(const short8*)(at + offA[ks] + 16 * CC);
            #pragma unroll
            for (int n = 0; n < 4; ++n) {
                acc[0][n] = __builtin_amdgcn_mfma_f32_16x16x32_bf16(a0, bWp[ks][n], acc[0][n], 0, 0, 0);
                acc[1][n] = __builtin_amdgcn_mfma_f32_16x16x32_bf16(a1, bWp[ks][n], acc[1][n], 0, 0, 0);
            }
        }
        {
            const short8 a0 = *(const short8*)(gt + offG);
            const short8 a1 = *(const short8*)(gt + offG + 16 * SG);
            #pragma unroll
            for (int n = 0; n < 4; ++n) {
                acc[0][n] = __builtin_amdgcn_mfma_f32_16x16x32_bf16(a0, bWp[4][n], acc[0][n], 0, 0, 0);
                acc[1][n] = __builtin_amdgcn_mfma_f32_16x16x32_bf16(a1, bWp[4][n], acc[1][n], 0, 0, 0);
            }
        }

        if (pair < GRP / 2 - 1) {
            geo_store(pair + 1, nb);
            if constexpr (!DMA) gather_store(nb);
        }

        // ---- relu + max-pool over 32 neighbors, residual, stash res ----
        const int prow = pair * 2 + ph;
        #pragma unroll
        for (int n = 0; n < 4; ++n) {
            float v = acc[0][n][0];
            #pragma unroll
            for (int r = 1; r < 4; ++r) v = fmaxf(v, acc[0][n][r]);
            #pragma unroll
            for (int r = 0; r < 4; ++r) v = fmaxf(v, acc[1][n][r]);
            v = fmaxf(v, __shfl_xor(v, 16));
            v = fmaxf(v, __shfl_xor(v, 32));
            v = fmaxf(v + beffv[n], 0.f);
            const float res = v + resc[n];
            if (quad == 0) sRes[prow * SR + ch * 64 + n * 16 + m] = f2bs(res);
        }
        #pragma unroll
        for (int n = 0; n < 4; ++n) resc[n] = resn[n];
        __syncthreads();
    }

    // ---- out projection: res(16x128) @ w_out(128x128); wave covers its 64 cols ----
    short8 bWo[4][4];
    #pragma unroll
    for (int ks = 0; ks < 4; ++ks)
        #pragma unroll
        for (int n = 0; n < 4; ++n)
            bWo[ks][n] = *((const short8*)wsWo + ((ks * 4 + quad) * 128 + ch * 64 + n * 16 + m));

    const short* rm = sRes + m * SR;
    float4v acc2[4] = {};
    #pragma unroll
    for (int ks = 0; ks < 4; ++ks) {
        const short8 a = *(const short8*)(rm + (ks * 4 + quad) * 8);
        #pragma unroll
        for (int n = 0; n < 4; ++n)
            acc2[n] = __builtin_amdgcn_mfma_f32_16x16x32_bf16(a, bWo[ks][n], acc2[n], 0, 0, 0);
    }

    float boutv[4], lngv[4], lnbv[4];
    #pragma unroll
    for (int n = 0; n < 4; ++n) {
        const int c = ch * 64 + n * 16 + m;
        boutv[n] = b_out[c]; lngv[n] = ln_g[c]; lnbv[n] = ln_b[c];
    }

    // ---- LayerNorm partials (rows R = quad*4+r), wave holds 64 cols ----
    #pragma unroll
    for (int r = 0; r < 4; ++r) {
        float ss = 0.f, qq = 0.f;
        #pragma unroll
        for (int n = 0; n < 4; ++n) {
            const float o = acc2[n][r] + boutv[n];
            ss += o; qq += o * o;
        }
        #pragma unroll
        for (int d = 1; d < 16; d <<= 1) { ss += __shfl_xor(ss, d); qq += __shfl_xor(qq, d); }
        if (m == 0) { sPS[wv][quad * 4 + r] = ss; sPQ[wv][quad * 4 + r] = qq; }
    }
    __syncthreads();

    if (wv < 2) {   // waves 0 (cols 0-63) and 1 (cols 64-127) write all outputs
        #pragma unroll
        for (int r = 0; r < 4; ++r) {
            const int R = quad * 4 + r;
            // ph-duplicated partials: sum all 4 waves and halve
            const float S = (sPS[0][R] + sPS[1][R] + sPS[2][R] + sPS[3][R]) * 0.5f;
            const float Q = (sPQ[0][R] + sPQ[1][R] + sPQ[2][R] + sPQ[3][R]) * 0.5f;
            const float mu  = S * (1.f / 128.f);
            const float var = fmaxf(Q * (1.f / 128.f) - mu * mu, 0.f);
            const float rstd = rsqrtf(var + LN_EPS);
            const size_t base = (size_t)(g0 + R) * CC;
            #pragma unroll
            for (int n = 0; n < 4; ++n) {
                const float o = acc2[n][r] + boutv[n];
                out[base + ch * 64 + n * 16 + m] = fmaxf((o - mu) * rstd * lngv[n] + lnbv[n], 0.f);
            }
        }
    }
}

extern "C" void kernel_launch(void* const* d_in, const int* in_sizes, int n_in,
                              void* d_out, int out_size, void* d_ws, size_t ws_size,
                              hipStream_t stream) {
    const float* points   = (const float*)d_in[0];
    const float* features = (const float*)d_in[1];
    const int*   gidx     = (const int*)  d_in[2];
    const float* w_pos    = (const float*)d_in[3];
    const float* b_pos    = (const float*)d_in[4];
    const float* w_gcm    = (const float*)d_in[5];
    const float* b_gcm    = (const float*)d_in[6];
    const float* w_out    = (const float*)d_in[7];
    const float* b_out    = (const float*)d_in[8];
    const float* ln_g     = (const float*)d_in[9];
    const float* ln_b     = (const float*)d_in[10];
    float* out = (float*)d_out;

    char* ws = (char*)d_ws;
    short*    wsWp   = (short*)(ws + WS_WP);
    short*    wsWo   = (short*)(ws + WS_WO);
    float*    wsBeff = (float*)(ws + WS_BE);
    ushort_t* featbf = (ushort_t*)(ws + WS_FB);

    const bool use_dma = (ws_size >= WS_NEED);

    hipLaunchKernelGGL(prep_weights, dim3(2), dim3(256), 0, stream,
                       w_pos, b_pos, w_gcm, b_gcm, w_out, wsWp, wsWo, wsBeff);
    if (use_dma) {
        hipLaunchKernelGGL(prep_convert, dim3(512), dim3(256), 0, stream, features, featbf);
        hipLaunchKernelGGL((bridge_main<1>), dim3(NPTS / GRP), dim3(256), 0, stream,
                           points, features, gidx, wsWp, wsWo, wsBeff, featbf,
                           b_out, ln_g, ln_b, out);
    } else {
        hipLaunchKernelGGL((bridge_main<0>), dim3(NPTS / GRP), dim3(256), 0, stream,
                           points, features, gidx, wsWp, wsWo, wsBeff, featbf,
                           b_out, ln_g, ln_b, out);
    }
}